// Round 8
// baseline (468.292 us; speedup 1.0000x reference)
//
#include <hip/hip_runtime.h>
#include <math.h>

#define TT 64
#define BB 64
#define DD 512
#define HH 512
#define G4 2048
#define OO 128

typedef unsigned short us16;
typedef __attribute__((ext_vector_type(8))) short bf16x8;
typedef __attribute__((ext_vector_type(4))) float f32x4;
typedef __attribute__((ext_vector_type(4))) unsigned u32x4;

__device__ __forceinline__ unsigned pk_bf16(float lo, float hi) {
  unsigned r;
  asm volatile("v_cvt_pk_bf16_f32 %0, %1, %2" : "=v"(r) : "v"(lo), "v"(hi));
  return r;
}

__device__ __forceinline__ float sigm(float v) { return 1.f / (1.f + expf(-v)); }

// coherent (LLC-direct) accesses for cross-block data
__device__ __forceinline__ u32x4 load_b128_cc(const void* p) {
  u32x4 r;
  asm volatile("global_load_dwordx4 %0, %1, off sc0 sc1" : "=v"(r) : "v"(p));
  return r;
}
__device__ __forceinline__ void store_b128_cc(void* p, u32x4 v) {
  asm volatile("global_store_dwordx4 %0, %1, off sc0 sc1" ::"v"(p), "v"(v) : "memory");
}

// ============================================================================
// Phase A: G[t,b,j] = x_t @ Wih_t^T + b_ih + b_hh   via bf16 MFMA  (unchanged)
// ============================================================================
__global__ __launch_bounds__(256) void phaseA_mfma(
    const float* __restrict__ x, const float* __restrict__ wih,
    const float* __restrict__ bih, const float* __restrict__ bhh,
    float* __restrict__ Gb) {
  __shared__ us16 xa[2][64][64];
  __shared__ us16 wbuf[2][128][64];
  const int tid = threadIdx.x;
  const int t = blockIdx.y;
  const int j0 = blockIdx.x * 128;
  const int wv = tid >> 6, lane = tid & 63;
  const int wm = wv & 1, wn = wv >> 1;
  const float* xb = x + (size_t)t * (BB * DD);
  const float* wg = wih + (size_t)t * (G4 * DD) + (size_t)j0 * DD;

  float4 xr[2][2], wr[4][2];
  int xrow[2], xc[2], wrow[4], wc[4];
#pragma unroll
  for (int i = 0; i < 2; i++) { int cid = tid + i * 256; xrow[i] = cid >> 3; xc[i] = cid & 7; }
#pragma unroll
  for (int i = 0; i < 4; i++) { int cid = tid + i * 256; wrow[i] = cid >> 3; wc[i] = cid & 7; }

  auto loadx = [&](int k0) {
#pragma unroll
    for (int i = 0; i < 2; i++) {
      const float* p = xb + xrow[i] * DD + k0 + xc[i] * 8;
      xr[i][0] = *(const float4*)p; xr[i][1] = *(const float4*)(p + 4);
    }
  };
  auto loadw = [&](int k0) {
#pragma unroll
    for (int i = 0; i < 4; i++) {
      const float* p = wg + (size_t)wrow[i] * DD + k0 + wc[i] * 8;
      wr[i][0] = *(const float4*)p; wr[i][1] = *(const float4*)(p + 4);
    }
  };
  auto store = [&](int buf) {
#pragma unroll
    for (int i = 0; i < 2; i++) {
      uint4 u;
      u.x = pk_bf16(xr[i][0].x, xr[i][0].y); u.y = pk_bf16(xr[i][0].z, xr[i][0].w);
      u.z = pk_bf16(xr[i][1].x, xr[i][1].y); u.w = pk_bf16(xr[i][1].z, xr[i][1].w);
      int p = xc[i] ^ (xrow[i] & 7);
      *(uint4*)&xa[buf][xrow[i]][p * 8] = u;
    }
#pragma unroll
    for (int i = 0; i < 4; i++) {
      uint4 u;
      u.x = pk_bf16(wr[i][0].x, wr[i][0].y); u.y = pk_bf16(wr[i][0].z, wr[i][0].w);
      u.z = pk_bf16(wr[i][1].x, wr[i][1].y); u.w = pk_bf16(wr[i][1].z, wr[i][1].w);
      int p = wc[i] ^ (wrow[i] & 7);
      *(uint4*)&wbuf[buf][wrow[i]][p * 8] = u;
    }
  };

  loadx(0); loadw(0); store(0);
  __syncthreads();

  f32x4 zero = {0.f, 0.f, 0.f, 0.f};
  f32x4 acc[2][4];
#pragma unroll
  for (int mt = 0; mt < 2; mt++)
#pragma unroll
    for (int nt = 0; nt < 4; nt++) acc[mt][nt] = zero;

  for (int s = 0; s < 8; s++) {
    const int nb = s & 1;
    if (s < 7) { loadx((s + 1) * 64); loadw((s + 1) * 64); }
#pragma unroll
    for (int ks = 0; ks < 2; ks++) {
      const int cc = ks * 4 + (lane >> 4);
      bf16x8 a[2], b[4];
#pragma unroll
      for (int mt = 0; mt < 2; mt++) {
        int r = wm * 32 + mt * 16 + (lane & 15);
        a[mt] = *(const bf16x8*)&xa[nb][r][(cc ^ (r & 7)) * 8];
      }
#pragma unroll
      for (int nt = 0; nt < 4; nt++) {
        int r = wn * 64 + nt * 16 + (lane & 15);
        b[nt] = *(const bf16x8*)&wbuf[nb][r][(cc ^ (r & 7)) * 8];
      }
#pragma unroll
      for (int mt = 0; mt < 2; mt++)
#pragma unroll
        for (int nt = 0; nt < 4; nt++)
          acc[mt][nt] = __builtin_amdgcn_mfma_f32_16x16x32_bf16(a[mt], b[nt], acc[mt][nt], 0, 0, 0);
    }
    __syncthreads();
    if (s < 7) store(nb ^ 1);
    __syncthreads();
  }

  float bias[4]; int jn[4];
#pragma unroll
  for (int nt = 0; nt < 4; nt++) {
    jn[nt] = j0 + wn * 64 + nt * 16 + (lane & 15);
    bias[nt] = bih[t * G4 + jn[nt]] + bhh[t * G4 + jn[nt]];
  }
#pragma unroll
  for (int mt = 0; mt < 2; mt++)
#pragma unroll
    for (int nt = 0; nt < 4; nt++)
#pragma unroll
      for (int e = 0; e < 4; e++) {
        int brow = wm * 32 + mt * 16 + (lane >> 4) * 4 + e;
        Gb[((size_t)t * BB + brow) * G4 + jn[nt]] = acc[mt][nt][e] + bias[nt];
      }
}

// ============================================================================
// Persistent LSTM stepper v3.
// 256 blocks (bh = bid&1 batch-half, ug = bid>>1 -> units ug*4..+3), 4 waves:
//   waves 0,1 (G): full-k GEMM (16 MFMA, batch-16-half wm=wv) + IN-WAVE epilogue
//     via LDS transpose (no barrier: per-wave LDS FIFO). c in regs. Publish
//     16B tagged records [8B = 4 bf16 h][tag][pad] straight from the wave.
//   waves 2,3 (W): stream Whh(t+1) -> wbuf LDS double buffer; 2-iteration-deep
//     register pipeline so each 16 KB half has ~2 steps of HBM time.
// Sync per step: ONE intra-block s_barrier + one cross-block publish->poll RT.
// ============================================================================
__global__ __launch_bounds__(256, 1) void lstm_persist(
    const float* __restrict__ whh, const float* __restrict__ Gb,
    const int* __restrict__ lengths, char* __restrict__ hb,
    float* __restrict__ hf) {
  __shared__ us16 wbuf[2][16][512];  // 32 KB bf16 W double buffer (swizzled)
  __shared__ float gmT[2][16][20];   // per-wave transpose scratch [wm][gate n][batch m]

  const int tid = threadIdx.x, bid = blockIdx.x;
  const int bh = bid & 1, ug = bid >> 1;
  const int wv = tid >> 6, lane = tid & 63;
  const int l15 = lane & 15, klg = lane >> 4;

  if (wv < 2) {
    // ---------------- GEMM + epilogue waves ----------------
    const int wm = wv;
    const int bm = bh * 32 + wm * 16 + l15;      // A-row batch (poll/MFMA role)
    const int u = l15 & 3;                        // epilogue unit (0..3)
    const int ml = klg * 4 + (l15 >> 2);          // epilogue local batch (0..15)
    const int bg = bh * 32 + wm * 16 + ml;        // epilogue global batch
    const int mylen = lengths[bg];
    float cst = 0.f;
    const char* crb = hb + (size_t)bm * 2048 + klg * 32;

    for (int t = 0; t < TT; t++) {
      // G-gate loads for the epilogue (plain, L2): 4 floats, quad-coalesced
      float g4[4];
      {
        const float* gp = Gb + ((size_t)t * BB + bg) * G4 + ug * 4 + u;
#pragma unroll
        for (int q = 0; q < 4; q++) g4[q] = gp[q * 512];
      }

      f32x4 acc = {0.f, 0.f, 0.f, 0.f};
      if (t > 0) {
        const char* sb = crb + (size_t)(t & 1) * 131072;
        const unsigned tg = (unsigned)t;
        u32x4 ra[16], rb[16];
        while (true) {  // data-carrying poll: 1 LLC RT on success
#pragma unroll
          for (int s = 0; s < 16; s++) {
            ra[s] = load_b128_cc(sb + s * 128);
            rb[s] = load_b128_cc(sb + s * 128 + 16);
          }
          asm volatile("s_waitcnt vmcnt(0)" ::: "memory");
          __builtin_amdgcn_sched_barrier(0);
          bool ok = true;
#pragma unroll
          for (int s = 0; s < 16; s++) ok = ok && (ra[s].z == tg) && (rb[s].z == tg);
          if (__all(ok)) break;
          __builtin_amdgcn_s_sleep(1);
        }
        __builtin_amdgcn_s_setprio(1);
        bf16x8 wf[16];
#pragma unroll
        for (int s = 0; s < 16; s++)
          wf[s] = *(const bf16x8*)&wbuf[t & 1][l15][((4 * s + klg) ^ (l15 & 7)) * 8];
        f32x4 a0 = {0.f, 0.f, 0.f, 0.f}, a1 = {0.f, 0.f, 0.f, 0.f};
#pragma unroll
        for (int s = 0; s < 16; s++) {
          u32x4 fa;
          fa.x = ra[s].x; fa.y = ra[s].y; fa.z = rb[s].x; fa.w = rb[s].y;
          if (s & 1)
            a1 = __builtin_amdgcn_mfma_f32_16x16x32_bf16(__builtin_bit_cast(bf16x8, fa), wf[s], a1, 0, 0, 0);
          else
            a0 = __builtin_amdgcn_mfma_f32_16x16x32_bf16(__builtin_bit_cast(bf16x8, fa), wf[s], a0, 0, 0, 0);
        }
        acc = a0 + a1;
      }

      // in-wave transpose: acc[e] = gates[n=l15][m=klg*4+e] -> lane (m,u) view
      *(f32x4*)&gmT[wm][l15][klg * 4] = acc;
      float vi = g4[0] + gmT[wm][0 + u][ml];
      float vf = g4[1] + gmT[wm][4 + u][ml];
      float vg = g4[2] + gmT[wm][8 + u][ml];
      float vo = g4[3] + gmT[wm][12 + u][ml];
      float cn = sigm(vf) * cst + sigm(vi) * tanhf(vg);
      cst = cn;
      float hv = sigm(vo) * tanhf(cn);
      if (mylen - 1 == t) hf[(size_t)bg * HH + ug * 4 + u] = hv;
      if (t + 1 < TT) {
        float ho = __shfl_xor(hv, 1);
        unsigned hp = pk_bf16(hv, ho);       // valid on even u
        unsigned hq = __shfl_xor(hp, 2);     // u0 <- u2's pair
        if (u == 0) {
          u32x4 rec;
          rec.x = hp; rec.y = hq; rec.z = (unsigned)(t + 1); rec.w = 0u;
          store_b128_cc(hb + (size_t)((t + 1) & 1) * 131072 + ((size_t)bg * 128 + ug) * 16, rec);
        }
      }
      __builtin_amdgcn_s_setprio(0);
      __builtin_amdgcn_s_barrier();
    }
  } else {
    // ---------------- W-streamer waves (2,3): 8 gate-rows each ----------------
    const int jb = (wv - 2) * 8;
    float4 a0[8], b0[8], a1[8], b1[8];
    auto issue = [&](int tt, float4* pa, float4* pb) {
      const float* wt = whh + (size_t)tt * (G4 * HH);
#pragma unroll
      for (int j = 0; j < 8; j++) {
        int jj = jb + j;
        const float* p = wt + (size_t)((jj >> 2) * 512 + ug * 4 + (jj & 3)) * HH + lane * 8;
        pa[j] = *(const float4*)p;
        pb[j] = *(const float4*)(p + 4);
      }
    };
    auto writeL = [&](int sl, float4* pa, float4* pb) {
#pragma unroll
      for (int j = 0; j < 8; j++) {
        int jj = jb + j;
        u32x4 w;
        w.x = pk_bf16(pa[j].x, pa[j].y); w.y = pk_bf16(pa[j].z, pa[j].w);
        w.z = pk_bf16(pb[j].x, pb[j].y); w.w = pk_bf16(pb[j].z, pb[j].w);
        *(u32x4*)&wbuf[sl][jj][(lane ^ (jj & 7)) * 8] = w;
      }
    };
    issue(1, a0, b0);  // W(1) -> set0
    for (int t = 0; t < TT; t++) {
      if (t & 1) {
        if (t + 2 < TT) issue(t + 2, a0, b0);
        if (t + 1 < TT) writeL((t + 1) & 1, a1, b1);
      } else {
        if (t + 2 < TT) issue(t + 2, a1, b1);
        if (t + 1 < TT) writeL((t + 1) & 1, a0, b0);
      }
      __builtin_amdgcn_s_barrier();
    }
  }
}

// ============================================================================
// Final: logits = hf @ w_ho^T + b_ho, then log_softmax
// ============================================================================
__global__ __launch_bounds__(128) void finalK(const float* __restrict__ hf,
                                              const float* __restrict__ who,
                                              const float* __restrict__ bho,
                                              float* __restrict__ out) {
  int b = blockIdx.x, o = threadIdx.x;
  const float* h = hf + b * HH;
  const float* w = who + o * HH;
  float s = bho[o];
#pragma unroll 4
  for (int k = 0; k < HH; k += 4) {
    float4 hv = *(const float4*)(h + k);
    float4 wv = *(const float4*)(w + k);
    s += hv.x * wv.x + hv.y * wv.y + hv.z * wv.z + hv.w * wv.w;
  }
  __shared__ float red[2];
  __shared__ float red2[2];
  float m = s;
#pragma unroll
  for (int msk = 32; msk; msk >>= 1) m = fmaxf(m, __shfl_xor(m, msk));
  int wave = o >> 6;
  if ((o & 63) == 0) red[wave] = m;
  __syncthreads();
  m = fmaxf(red[0], red[1]);
  float e = expf(s - m);
#pragma unroll
  for (int msk = 32; msk; msk >>= 1) e += __shfl_xor(e, msk);
  if ((o & 63) == 0) red2[wave] = e;
  __syncthreads();
  float sum = red2[0] + red2[1];
  out[b * OO + o] = (s - m) - logf(sum);
}

extern "C" void kernel_launch(void* const* d_in, const int* in_sizes, int n_in,
                              void* d_out, int out_size, void* d_ws, size_t ws_size,
                              hipStream_t stream) {
  const float* x = (const float*)d_in[0];
  const float* wih = (const float*)d_in[1];
  const float* whh = (const float*)d_in[2];
  const float* bih = (const float*)d_in[3];
  const float* bhh = (const float*)d_in[4];
  const float* who = (const float*)d_in[5];
  const float* bho = (const float*)d_in[6];
  const int* lengths = (const int*)d_in[7];
  float* out = (float*)d_out;

  char* ws = (char*)d_ws;
  float* Gb = (float*)ws;                        // 33,554,432 B
  char* hb = ws + 33554432;                      // 262,144 B (2 slots x 64 b x 128 u4 x 16 B)
  float* hf = (float*)(ws + 33554432 + 262144);  // 131,072 B

  (void)hipMemsetAsync(hb, 0, 262144, stream);  // clear tags (replay safety)

  phaseA_mfma<<<dim3(16, 64), 256, 0, stream>>>(x, wih, bih, bhh, Gb);
  lstm_persist<<<256, 256, 0, stream>>>(whh, Gb, lengths, hb, hf);
  finalK<<<BB, 128, 0, stream>>>(hf, who, bho, out);
}

// Round 9
// 410.943 us; speedup vs baseline: 1.1396x; 1.1396x over previous
//
#include <hip/hip_runtime.h>
#include <math.h>

#define TT 64
#define BB 64
#define DD 512
#define HH 512
#define G4 2048
#define OO 128

typedef unsigned short us16;
typedef __attribute__((ext_vector_type(8))) short bf16x8;
typedef __attribute__((ext_vector_type(4))) float f32x4;
typedef __attribute__((ext_vector_type(4))) unsigned u32x4;

__device__ __forceinline__ unsigned pk_bf16(float lo, float hi) {
  unsigned r;
  asm volatile("v_cvt_pk_bf16_f32 %0, %1, %2" : "=v"(r) : "v"(lo), "v"(hi));
  return r;
}

__device__ __forceinline__ float sigm(float v) { return 1.f / (1.f + expf(-v)); }

// coherent (LLC-direct) accesses for cross-block data
__device__ __forceinline__ u32x4 load_b128_cc(const void* p) {
  u32x4 r;
  asm volatile("global_load_dwordx4 %0, %1, off sc0 sc1" : "=v"(r) : "v"(p));
  return r;
}
__device__ __forceinline__ void store_b128_cc(void* p, u32x4 v) {
  asm volatile("global_store_dwordx4 %0, %1, off sc0 sc1" ::"v"(p), "v"(v) : "memory");
}

// ============================================================================
// Phase A: G[t,b,j] = x_t @ Wih_t^T + b_ih + b_hh   via bf16 MFMA  (unchanged)
// ============================================================================
__global__ __launch_bounds__(256) void phaseA_mfma(
    const float* __restrict__ x, const float* __restrict__ wih,
    const float* __restrict__ bih, const float* __restrict__ bhh,
    float* __restrict__ Gb) {
  __shared__ us16 xa[2][64][64];
  __shared__ us16 wbuf[2][128][64];
  const int tid = threadIdx.x;
  const int t = blockIdx.y;
  const int j0 = blockIdx.x * 128;
  const int wv = tid >> 6, lane = tid & 63;
  const int wm = wv & 1, wn = wv >> 1;
  const float* xb = x + (size_t)t * (BB * DD);
  const float* wg = wih + (size_t)t * (G4 * DD) + (size_t)j0 * DD;

  float4 xr[2][2], wr[4][2];
  int xrow[2], xc[2], wrow[4], wc[4];
#pragma unroll
  for (int i = 0; i < 2; i++) { int cid = tid + i * 256; xrow[i] = cid >> 3; xc[i] = cid & 7; }
#pragma unroll
  for (int i = 0; i < 4; i++) { int cid = tid + i * 256; wrow[i] = cid >> 3; wc[i] = cid & 7; }

  auto loadx = [&](int k0) {
#pragma unroll
    for (int i = 0; i < 2; i++) {
      const float* p = xb + xrow[i] * DD + k0 + xc[i] * 8;
      xr[i][0] = *(const float4*)p; xr[i][1] = *(const float4*)(p + 4);
    }
  };
  auto loadw = [&](int k0) {
#pragma unroll
    for (int i = 0; i < 4; i++) {
      const float* p = wg + (size_t)wrow[i] * DD + k0 + wc[i] * 8;
      wr[i][0] = *(const float4*)p; wr[i][1] = *(const float4*)(p + 4);
    }
  };
  auto store = [&](int buf) {
#pragma unroll
    for (int i = 0; i < 2; i++) {
      uint4 u;
      u.x = pk_bf16(xr[i][0].x, xr[i][0].y); u.y = pk_bf16(xr[i][0].z, xr[i][0].w);
      u.z = pk_bf16(xr[i][1].x, xr[i][1].y); u.w = pk_bf16(xr[i][1].z, xr[i][1].w);
      int p = xc[i] ^ (xrow[i] & 7);
      *(uint4*)&xa[buf][xrow[i]][p * 8] = u;
    }
#pragma unroll
    for (int i = 0; i < 4; i++) {
      uint4 u;
      u.x = pk_bf16(wr[i][0].x, wr[i][0].y); u.y = pk_bf16(wr[i][0].z, wr[i][0].w);
      u.z = pk_bf16(wr[i][1].x, wr[i][1].y); u.w = pk_bf16(wr[i][1].z, wr[i][1].w);
      int p = wc[i] ^ (wrow[i] & 7);
      *(uint4*)&wbuf[buf][wrow[i]][p * 8] = u;
    }
  };

  loadx(0); loadw(0); store(0);
  __syncthreads();

  f32x4 zero = {0.f, 0.f, 0.f, 0.f};
  f32x4 acc[2][4];
#pragma unroll
  for (int mt = 0; mt < 2; mt++)
#pragma unroll
    for (int nt = 0; nt < 4; nt++) acc[mt][nt] = zero;

  for (int s = 0; s < 8; s++) {
    const int nb = s & 1;
    if (s < 7) { loadx((s + 1) * 64); loadw((s + 1) * 64); }
#pragma unroll
    for (int ks = 0; ks < 2; ks++) {
      const int cc = ks * 4 + (lane >> 4);
      bf16x8 a[2], b[4];
#pragma unroll
      for (int mt = 0; mt < 2; mt++) {
        int r = wm * 32 + mt * 16 + (lane & 15);
        a[mt] = *(const bf16x8*)&xa[nb][r][(cc ^ (r & 7)) * 8];
      }
#pragma unroll
      for (int nt = 0; nt < 4; nt++) {
        int r = wn * 64 + nt * 16 + (lane & 15);
        b[nt] = *(const bf16x8*)&wbuf[nb][r][(cc ^ (r & 7)) * 8];
      }
#pragma unroll
      for (int mt = 0; mt < 2; mt++)
#pragma unroll
        for (int nt = 0; nt < 4; nt++)
          acc[mt][nt] = __builtin_amdgcn_mfma_f32_16x16x32_bf16(a[mt], b[nt], acc[mt][nt], 0, 0, 0);
    }
    __syncthreads();
    if (s < 7) store(nb ^ 1);
    __syncthreads();
  }

  float bias[4]; int jn[4];
#pragma unroll
  for (int nt = 0; nt < 4; nt++) {
    jn[nt] = j0 + wn * 64 + nt * 16 + (lane & 15);
    bias[nt] = bih[t * G4 + jn[nt]] + bhh[t * G4 + jn[nt]];
  }
#pragma unroll
  for (int mt = 0; mt < 2; mt++)
#pragma unroll
    for (int nt = 0; nt < 4; nt++)
#pragma unroll
      for (int e = 0; e < 4; e++) {
        int brow = wm * 32 + mt * 16 + (lane >> 4) * 4 + e;
        Gb[((size_t)t * BB + brow) * G4 + jn[nt]] = acc[mt][nt][e] + bias[nt];
      }
}

// ============================================================================
// Persistent LSTM stepper (round-6 structure, reordered prefetch).
// 256 blocks (bh = bid&1, ug = bid>>1 -> units ug*4..+3), 4 waves
// (wm = wv&1 -> batch-16-half, kq = wv>>1 -> k-256-half).
// h in global as 16B TAGGED RECORDS [8B = 4 bf16 h][4B tag][pad], 2-slot
// ping-pong, sc0/sc1 only. Publish = the data store; poll = data-carrying.
// Per-step order: poll -> gcur copy -> cvtW -> prefW/prefG(t+1) -> MFMA ->
// lgkmcnt(0) + RAW s_barrier (no vmcnt drain!) -> wave0 epilogue + publish.
// W(t+1) thus streams across the whole next-step window instead of being
// drained serially before the poll (round 6's hidden stall).
// ============================================================================
__global__ __launch_bounds__(256, 1) void lstm_persist(
    const float* __restrict__ whh, const float* __restrict__ Gb,
    const int* __restrict__ lengths, char* __restrict__ hb,
    float* __restrict__ hf) {
  __shared__ float gm[2][16][36];

  const int tid = threadIdx.x, bid = blockIdx.x;
  const int bh = bid & 1, ug = bid >> 1;
  const int wv = tid >> 6, lane = tid & 63;
  const int wm = wv & 1, kq = wv >> 1;
  const int l15 = lane & 15, klg = lane >> 4;

  // B-fragment source row in Whh: ri = l15 -> gate q = ri>>2, unit u = ri&3
  const size_t jrow = (size_t)((l15 >> 2) * 512 + ug * 4 + (l15 & 3));

  float4 pf[8][2];  // W(t+1) fp32 in-flight registers
  auto prefW = [&](int tt) {
    const float* wt = whh + (size_t)tt * (G4 * HH) + jrow * HH;
#pragma unroll
    for (int s = 0; s < 8; s++) {
      const float* p = wt + (size_t)(kq * 32 + s * 4 + klg) * 8;
      pf[s][0] = *(const float4*)p;
      pf[s][1] = *(const float4*)(p + 4);
    }
  };
  bf16x8 wfrag[8];
  auto cvtW = [&]() {
#pragma unroll
    for (int s = 0; s < 8; s++) {
      uint4 u;
      u.x = pk_bf16(pf[s][0].x, pf[s][0].y); u.y = pk_bf16(pf[s][0].z, pf[s][0].w);
      u.z = pk_bf16(pf[s][1].x, pf[s][1].y); u.w = pk_bf16(pf[s][1].z, pf[s][1].w);
      wfrag[s] = __builtin_bit_cast(bf16x8, u);
    }
  };

  float2 gpre[4];  // Gb prefetch (wave0, 64 lanes: 2 units each)
  auto prefG = [&](int tt) {
    if (tid < 64) {
      const float* gbp =
          Gb + ((size_t)tt * BB + bh * 32 + (lane & 31)) * G4 + ug * 4 + ((lane >> 5) << 1);
#pragma unroll
      for (int q = 0; q < 4; q++) gpre[q] = *(const float2*)(gbp + q * 512);
    }
  };

  // consumer record base: record (u4, m) at half_base + (u4*32 + m)*16
  const size_t cbase =
      (size_t)bh * 65536 + ((size_t)(kq * 64 + klg * 2) * 32 + wm * 16 + l15) * 16;
  // producer (wave0, lanes 0..31): u4 = ug, m = lane
  const size_t pbase = (size_t)bh * 65536 + ((size_t)ug * 32 + (lane & 31)) * 16;

  const int mylen = (wv == 0) ? lengths[bh * 32 + (lane & 31)] : -2;
  float cst[2] = {0.f, 0.f};  // c state in registers (wave0 lanes, 2 units each)

  prefW(0);
  prefG(0);

  for (int t = 0; t < TT; t++) {
    // ---- 1. poll records(t): data-carrying, 1 LLC RT on success ----
    u32x4 r0[8], r1[8];
    if (t == 0) {
      u32x4 z = {0u, 0u, 0u, 0u};
#pragma unroll
      for (int s = 0; s < 8; s++) { r0[s] = z; r1[s] = z; }
    } else {
      const char* sbase = hb + (size_t)(t & 1) * 131072 + cbase;
      const unsigned tg = (unsigned)t;
      bool ok;
      do {
#pragma unroll
        for (int s = 0; s < 8; s++) {
          r0[s] = load_b128_cc(sbase + (size_t)s * 4096);
          r1[s] = load_b128_cc(sbase + (size_t)s * 4096 + 512);
        }
        asm volatile("s_waitcnt vmcnt(0)" ::: "memory");
        __builtin_amdgcn_sched_barrier(0);
        ok = true;
#pragma unroll
        for (int s = 0; s < 8; s++) ok = ok && (r0[s].z == tg) && (r1[s].z == tg);
      } while (!__all(ok));
    }

    // ---- 2. snapshot G(t) before re-issuing prefetch ----
    float2 gcur[4];
    if (wv == 0) {
#pragma unroll
      for (int q = 0; q < 4; q++) gcur[q] = gpre[q];
    }

    // ---- 3. W(t) regs -> bf16 fragments (loads already drained by poll) ----
    cvtW();

    // ---- 4. issue W(t+1)/G(t+1): streams across MFMA+barrier+epilogue+poll ----
    if (t + 1 < TT) { prefW(t + 1); prefG(t + 1); }

    // ---- 5. recurrent MFMA ----
    f32x4 acc = {0.f, 0.f, 0.f, 0.f};
#pragma unroll
    for (int s = 0; s < 8; s++) {
      u32x4 fa;
      fa.x = r0[s].x; fa.y = r0[s].y; fa.z = r1[s].x; fa.w = r1[s].y;
      acc = __builtin_amdgcn_mfma_f32_16x16x32_bf16(__builtin_bit_cast(bf16x8, fa),
                                                    wfrag[s], acc, 0, 0, 0);
    }
    *(f32x4*)&gm[kq][l15][wm * 16 + klg * 4] = acc;

    // ---- 6. LDS-only barrier: do NOT drain the W(t+1) vmem stream ----
    asm volatile("s_waitcnt lgkmcnt(0)" ::: "memory");
    __builtin_amdgcn_s_barrier();
    asm volatile("" ::: "memory");

    // ---- 7. epilogue + publish (wave 0) ----
    if (wv == 0) {
      const int b = lane & 31, hi = lane >> 5;
      float hv[2];
#pragma unroll
      for (int uu = 0; uu < 2; uu++) {
        const int lu = hi * 2 + uu;
        float vi = (uu ? gcur[0].y : gcur[0].x) + gm[0][0 + lu][b] + gm[1][0 + lu][b];
        float vf = (uu ? gcur[1].y : gcur[1].x) + gm[0][4 + lu][b] + gm[1][4 + lu][b];
        float vg = (uu ? gcur[2].y : gcur[2].x) + gm[0][8 + lu][b] + gm[1][8 + lu][b];
        float vo = (uu ? gcur[3].y : gcur[3].x) + gm[0][12 + lu][b] + gm[1][12 + lu][b];
        float cn = sigm(vf) * cst[uu] + sigm(vi) * tanhf(vg);
        cst[uu] = cn;
        hv[uu] = sigm(vo) * tanhf(cn);
      }
      unsigned hw = pk_bf16(hv[0], hv[1]);
      unsigned other = __shfl_xor(hw, 32);
      if (mylen - 1 == t) {
        float2 o2; o2.x = hv[0]; o2.y = hv[1];
        *(float2*)&hf[(size_t)(bh * 32 + b) * HH + ug * 4 + hi * 2] = o2;
      }
      if (hi == 0 && t + 1 < TT) {
        u32x4 rec;
        rec.x = hw; rec.y = other; rec.z = (unsigned)(t + 1); rec.w = 0u;
        store_b128_cc(hb + (size_t)((t + 1) & 1) * 131072 + pbase, rec);
      }
    }
  }
}

// ============================================================================
// Final: logits = hf @ w_ho^T + b_ho, then log_softmax
// ============================================================================
__global__ __launch_bounds__(128) void finalK(const float* __restrict__ hf,
                                              const float* __restrict__ who,
                                              const float* __restrict__ bho,
                                              float* __restrict__ out) {
  int b = blockIdx.x, o = threadIdx.x;
  const float* h = hf + b * HH;
  const float* w = who + o * HH;
  float s = bho[o];
#pragma unroll 4
  for (int k = 0; k < HH; k += 4) {
    float4 hv = *(const float4*)(h + k);
    float4 wv = *(const float4*)(w + k);
    s += hv.x * wv.x + hv.y * wv.y + hv.z * wv.z + hv.w * wv.w;
  }
  __shared__ float red[2];
  __shared__ float red2[2];
  float m = s;
#pragma unroll
  for (int msk = 32; msk; msk >>= 1) m = fmaxf(m, __shfl_xor(m, msk));
  int wave = o >> 6;
  if ((o & 63) == 0) red[wave] = m;
  __syncthreads();
  m = fmaxf(red[0], red[1]);
  float e = expf(s - m);
#pragma unroll
  for (int msk = 32; msk; msk >>= 1) e += __shfl_xor(e, msk);
  if ((o & 63) == 0) red2[wave] = e;
  __syncthreads();
  float sum = red2[0] + red2[1];
  out[b * OO + o] = (s - m) - logf(sum);
}

extern "C" void kernel_launch(void* const* d_in, const int* in_sizes, int n_in,
                              void* d_out, int out_size, void* d_ws, size_t ws_size,
                              hipStream_t stream) {
  const float* x = (const float*)d_in[0];
  const float* wih = (const float*)d_in[1];
  const float* whh = (const float*)d_in[2];
  const float* bih = (const float*)d_in[3];
  const float* bhh = (const float*)d_in[4];
  const float* who = (const float*)d_in[5];
  const float* bho = (const float*)d_in[6];
  const int* lengths = (const int*)d_in[7];
  float* out = (float*)d_out;

  char* ws = (char*)d_ws;
  float* Gb = (float*)ws;                        // 33,554,432 B
  char* hb = ws + 33554432;                      // 262,144 B (2 slots x 2 halves x 4096 records)
  float* hf = (float*)(ws + 33554432 + 262144);  // 131,072 B

  (void)hipMemsetAsync(hb, 0, 262144, stream);  // clear tags (graph-replay safety)

  phaseA_mfma<<<dim3(16, 64), 256, 0, stream>>>(x, wih, bih, bhh, Gb);
  lstm_persist<<<256, 256, 0, stream>>>(whh, Gb, lengths, hb, hf);
  finalK<<<BB, 128, 0, stream>>>(hf, who, bho, out);
}

// Round 10
// 341.828 us; speedup vs baseline: 1.3700x; 1.2022x over previous
//
#include <hip/hip_runtime.h>
#include <math.h>

#define TT 64
#define BB 64
#define DD 512
#define HH 512
#define G4 2048
#define OO 128

typedef unsigned short us16;
typedef __attribute__((ext_vector_type(8))) short bf16x8;
typedef __attribute__((ext_vector_type(4))) float f32x4;
typedef __attribute__((ext_vector_type(4))) unsigned u32x4;

__device__ __forceinline__ unsigned pk_bf16(float lo, float hi) {
  unsigned r;
  asm volatile("v_cvt_pk_bf16_f32 %0, %1, %2" : "=v"(r) : "v"(lo), "v"(hi));
  return r;
}

__device__ __forceinline__ float sigm(float v) { return 1.f / (1.f + expf(-v)); }
// fast variants for the publish-critical epilogue (bf16 tolerance is ample)
__device__ __forceinline__ float fsigm(float v) { return 1.f / (1.f + __expf(-v)); }
__device__ __forceinline__ float ftanh(float v) { return 1.f - 2.f / (__expf(2.f * v) + 1.f); }

// coherent (LLC-direct) accesses for cross-block data
__device__ __forceinline__ u32x4 load_b128_cc(const void* p) {
  u32x4 r;
  asm volatile("global_load_dwordx4 %0, %1, off sc0 sc1" : "=v"(r) : "v"(p));
  return r;
}
__device__ __forceinline__ void store_b128_cc(void* p, u32x4 v) {
  asm volatile("global_store_dwordx4 %0, %1, off sc0 sc1" ::"v"(p), "v"(v) : "memory");
}

// ============================================================================
// Phase A: G[t,b,j] = x_t @ Wih_t^T + b_ih + b_hh   via bf16 MFMA  (unchanged)
// ============================================================================
__global__ __launch_bounds__(256) void phaseA_mfma(
    const float* __restrict__ x, const float* __restrict__ wih,
    const float* __restrict__ bih, const float* __restrict__ bhh,
    float* __restrict__ Gb) {
  __shared__ us16 xa[2][64][64];
  __shared__ us16 wbuf[2][128][64];
  const int tid = threadIdx.x;
  const int t = blockIdx.y;
  const int j0 = blockIdx.x * 128;
  const int wv = tid >> 6, lane = tid & 63;
  const int wm = wv & 1, wn = wv >> 1;
  const float* xb = x + (size_t)t * (BB * DD);
  const float* wg = wih + (size_t)t * (G4 * DD) + (size_t)j0 * DD;

  float4 xr[2][2], wr[4][2];
  int xrow[2], xc[2], wrow[4], wc[4];
#pragma unroll
  for (int i = 0; i < 2; i++) { int cid = tid + i * 256; xrow[i] = cid >> 3; xc[i] = cid & 7; }
#pragma unroll
  for (int i = 0; i < 4; i++) { int cid = tid + i * 256; wrow[i] = cid >> 3; wc[i] = cid & 7; }

  auto loadx = [&](int k0) {
#pragma unroll
    for (int i = 0; i < 2; i++) {
      const float* p = xb + xrow[i] * DD + k0 + xc[i] * 8;
      xr[i][0] = *(const float4*)p; xr[i][1] = *(const float4*)(p + 4);
    }
  };
  auto loadw = [&](int k0) {
#pragma unroll
    for (int i = 0; i < 4; i++) {
      const float* p = wg + (size_t)wrow[i] * DD + k0 + wc[i] * 8;
      wr[i][0] = *(const float4*)p; wr[i][1] = *(const float4*)(p + 4);
    }
  };
  auto store = [&](int buf) {
#pragma unroll
    for (int i = 0; i < 2; i++) {
      uint4 u;
      u.x = pk_bf16(xr[i][0].x, xr[i][0].y); u.y = pk_bf16(xr[i][0].z, xr[i][0].w);
      u.z = pk_bf16(xr[i][1].x, xr[i][1].y); u.w = pk_bf16(xr[i][1].z, xr[i][1].w);
      int p = xc[i] ^ (xrow[i] & 7);
      *(uint4*)&xa[buf][xrow[i]][p * 8] = u;
    }
#pragma unroll
    for (int i = 0; i < 4; i++) {
      uint4 u;
      u.x = pk_bf16(wr[i][0].x, wr[i][0].y); u.y = pk_bf16(wr[i][0].z, wr[i][0].w);
      u.z = pk_bf16(wr[i][1].x, wr[i][1].y); u.w = pk_bf16(wr[i][1].z, wr[i][1].w);
      int p = wc[i] ^ (wrow[i] & 7);
      *(uint4*)&wbuf[buf][wrow[i]][p * 8] = u;
    }
  };

  loadx(0); loadw(0); store(0);
  __syncthreads();

  f32x4 zero = {0.f, 0.f, 0.f, 0.f};
  f32x4 acc[2][4];
#pragma unroll
  for (int mt = 0; mt < 2; mt++)
#pragma unroll
    for (int nt = 0; nt < 4; nt++) acc[mt][nt] = zero;

  for (int s = 0; s < 8; s++) {
    const int nb = s & 1;
    if (s < 7) { loadx((s + 1) * 64); loadw((s + 1) * 64); }
#pragma unroll
    for (int ks = 0; ks < 2; ks++) {
      const int cc = ks * 4 + (lane >> 4);
      bf16x8 a[2], b[4];
#pragma unroll
      for (int mt = 0; mt < 2; mt++) {
        int r = wm * 32 + mt * 16 + (lane & 15);
        a[mt] = *(const bf16x8*)&xa[nb][r][(cc ^ (r & 7)) * 8];
      }
#pragma unroll
      for (int nt = 0; nt < 4; nt++) {
        int r = wn * 64 + nt * 16 + (lane & 15);
        b[nt] = *(const bf16x8*)&wbuf[nb][r][(cc ^ (r & 7)) * 8];
      }
#pragma unroll
      for (int mt = 0; mt < 2; mt++)
#pragma unroll
        for (int nt = 0; nt < 4; nt++)
          acc[mt][nt] = __builtin_amdgcn_mfma_f32_16x16x32_bf16(a[mt], b[nt], acc[mt][nt], 0, 0, 0);
    }
    __syncthreads();
    if (s < 7) store(nb ^ 1);
    __syncthreads();
  }

  float bias[4]; int jn[4];
#pragma unroll
  for (int nt = 0; nt < 4; nt++) {
    jn[nt] = j0 + wn * 64 + nt * 16 + (lane & 15);
    bias[nt] = bih[t * G4 + jn[nt]] + bhh[t * G4 + jn[nt]];
  }
#pragma unroll
  for (int mt = 0; mt < 2; mt++)
#pragma unroll
    for (int nt = 0; nt < 4; nt++)
#pragma unroll
      for (int e = 0; e < 4; e++) {
        int brow = wm * 32 + mt * 16 + (lane >> 4) * 4 + e;
        Gb[((size_t)t * BB + brow) * G4 + jn[nt]] = acc[mt][nt][e] + bias[nt];
      }
}

// ============================================================================
// Persistent LSTM stepper — EXACT round-6 structure (measured best, 265 us)
// with three publish-path cuts:
//   (1) s_sleep(1) backoff on failed poll sweeps (LLC contention),
//   (2) __expf-based gate math in the epilogue,
//   (3) publish record before the hf side-store.
// 256 blocks (bh = bid&1, ug = bid>>1 -> units ug*4..+3), 4 waves
// (wm = wv&1 -> batch-16-half, kq = wv>>1 -> k-256-half).
// h in global as 16B TAGGED RECORDS [8B = 4 bf16 h][4B tag][pad], 2-slot
// ping-pong, sc0/sc1 only. Publish = the data store; poll = data-carrying.
// ============================================================================
__global__ __launch_bounds__(256, 1) void lstm_persist(
    const float* __restrict__ whh, const float* __restrict__ Gb,
    const int* __restrict__ lengths, char* __restrict__ hb,
    float* __restrict__ hf) {
  __shared__ float gm[2][16][36];

  const int tid = threadIdx.x, bid = blockIdx.x;
  const int bh = bid & 1, ug = bid >> 1;
  const int wv = tid >> 6, lane = tid & 63;
  const int wm = wv & 1, kq = wv >> 1;
  const int l15 = lane & 15, klg = lane >> 4;

  // B-fragment source row in Whh: ri = l15 -> gate q = ri>>2, unit u = ri&3
  const size_t jrow = (size_t)((l15 >> 2) * 512 + ug * 4 + (l15 & 3));

  float4 pf[8][2];  // W(t) fp32 prefetch
  auto prefW = [&](int tt) {
    const float* wt = whh + (size_t)tt * (G4 * HH) + jrow * HH;
#pragma unroll
    for (int s = 0; s < 8; s++) {
      const float* p = wt + (size_t)(kq * 32 + s * 4 + klg) * 8;
      pf[s][0] = *(const float4*)p;
      pf[s][1] = *(const float4*)(p + 4);
    }
  };
  bf16x8 wfrag[8];
  auto cvtW = [&]() {
#pragma unroll
    for (int s = 0; s < 8; s++) {
      uint4 u;
      u.x = pk_bf16(pf[s][0].x, pf[s][0].y); u.y = pk_bf16(pf[s][0].z, pf[s][0].w);
      u.z = pk_bf16(pf[s][1].x, pf[s][1].y); u.w = pk_bf16(pf[s][1].z, pf[s][1].w);
      wfrag[s] = __builtin_bit_cast(bf16x8, u);
    }
  };

  float2 gpre[4];  // Gb prefetch (wave0, 64 lanes: 2 units each)
  auto prefG = [&](int tt) {
    if (wv == 0) {
      const float* gbp =
          Gb + ((size_t)tt * BB + bh * 32 + (lane & 31)) * G4 + ug * 4 + ((lane >> 5) << 1);
#pragma unroll
      for (int q = 0; q < 4; q++) gpre[q] = *(const float2*)(gbp + q * 512);
    }
  };

  // consumer record base: record (u4, m) at half_base + (u4*32 + m)*16
  const size_t cbase =
      (size_t)bh * 65536 + ((size_t)(kq * 64 + klg * 2) * 32 + wm * 16 + l15) * 16;
  // producer (wave0, lanes 0..31): u4 = ug, m = lane
  const size_t pbase = (size_t)bh * 65536 + ((size_t)ug * 32 + (lane & 31)) * 16;

  const int mylen = (wv == 0) ? lengths[bh * 32 + (lane & 31)] : -2;
  float cst[2] = {0.f, 0.f};  // c state in registers (wave0 lanes, 2 units each)

  prefW(0);
  prefG(0);

  for (int t = 0; t < TT; t++) {
    cvtW();  // consume pf (drains W loads) -> acts as natural poll backoff

    u32x4 r0[8], r1[8];
    if (t == 0) {
      u32x4 z = {0u, 0u, 0u, 0u};
#pragma unroll
      for (int s = 0; s < 8; s++) { r0[s] = z; r1[s] = z; }
    } else {
      const char* sbase = hb + (size_t)(t & 1) * 131072 + cbase;
      const unsigned tg = (unsigned)t;
      bool ok;
      do {
#pragma unroll
        for (int s = 0; s < 8; s++) {
          r0[s] = load_b128_cc(sbase + (size_t)s * 4096);
          r1[s] = load_b128_cc(sbase + (size_t)s * 4096 + 512);
        }
        asm volatile("s_waitcnt vmcnt(0)" ::: "memory");
        __builtin_amdgcn_sched_barrier(0);
        ok = true;
#pragma unroll
        for (int s = 0; s < 8; s++) ok = ok && (r0[s].z == tg) && (r1[s].z == tg);
        if (!__all(ok)) {
          __builtin_amdgcn_s_sleep(1);  // backoff: don't hammer the LLC
          ok = false;
        } else {
          ok = true;
        }
      } while (!ok);
    }

    f32x4 acc = {0.f, 0.f, 0.f, 0.f};
#pragma unroll
    for (int s = 0; s < 8; s++) {
      u32x4 fa;
      fa.x = r0[s].x; fa.y = r0[s].y; fa.z = r1[s].x; fa.w = r1[s].y;
      acc = __builtin_amdgcn_mfma_f32_16x16x32_bf16(__builtin_bit_cast(bf16x8, fa),
                                                    wfrag[s], acc, 0, 0, 0);
    }
    *(f32x4*)&gm[kq][l15][wm * 16 + klg * 4] = acc;

    __syncthreads();

    float2 gcur[4];
    if (wv == 0) {
#pragma unroll
      for (int q = 0; q < 4; q++) gcur[q] = gpre[q];
    }
    // W/G prefetch for t+1: streams during epilogue + next poll, off critical path
    if (t + 1 < TT) { prefW(t + 1); prefG(t + 1); }

    if (wv == 0) {
      const int b = lane & 31, hi = lane >> 5;
      float hv[2];
#pragma unroll
      for (int uu = 0; uu < 2; uu++) {
        const int lu = hi * 2 + uu;
        float vi = (uu ? gcur[0].y : gcur[0].x) + gm[0][0 + lu][b] + gm[1][0 + lu][b];
        float vf = (uu ? gcur[1].y : gcur[1].x) + gm[0][4 + lu][b] + gm[1][4 + lu][b];
        float vg = (uu ? gcur[2].y : gcur[2].x) + gm[0][8 + lu][b] + gm[1][8 + lu][b];
        float vo = (uu ? gcur[3].y : gcur[3].x) + gm[0][12 + lu][b] + gm[1][12 + lu][b];
        float cn = fsigm(vf) * cst[uu] + fsigm(vi) * ftanh(vg);
        cst[uu] = cn;
        hv[uu] = fsigm(vo) * ftanh(cn);
      }
      // publish FIRST (cross-block critical path), hf store after
      unsigned hw = pk_bf16(hv[0], hv[1]);
      unsigned other = __shfl_xor(hw, 32);
      if (hi == 0 && t + 1 < TT) {
        u32x4 rec;
        rec.x = hw; rec.y = other; rec.z = (unsigned)(t + 1); rec.w = 0u;
        store_b128_cc(hb + (size_t)((t + 1) & 1) * 131072 + pbase, rec);
      }
      if (mylen - 1 == t) {
        float2 o2; o2.x = hv[0]; o2.y = hv[1];
        *(float2*)&hf[(size_t)(bh * 32 + b) * HH + ug * 4 + hi * 2] = o2;
      }
    }
  }
}

// ============================================================================
// Final: logits = hf @ w_ho^T + b_ho, then log_softmax
// ============================================================================
__global__ __launch_bounds__(128) void finalK(const float* __restrict__ hf,
                                              const float* __restrict__ who,
                                              const float* __restrict__ bho,
                                              float* __restrict__ out) {
  int b = blockIdx.x, o = threadIdx.x;
  const float* h = hf + b * HH;
  const float* w = who + o * HH;
  float s = bho[o];
#pragma unroll 4
  for (int k = 0; k < HH; k += 4) {
    float4 hv = *(const float4*)(h + k);
    float4 wv = *(const float4*)(w + k);
    s += hv.x * wv.x + hv.y * wv.y + hv.z * wv.z + hv.w * wv.w;
  }
  __shared__ float red[2];
  __shared__ float red2[2];
  float m = s;
#pragma unroll
  for (int msk = 32; msk; msk >>= 1) m = fmaxf(m, __shfl_xor(m, msk));
  int wave = o >> 6;
  if ((o & 63) == 0) red[wave] = m;
  __syncthreads();
  m = fmaxf(red[0], red[1]);
  float e = expf(s - m);
#pragma unroll
  for (int msk = 32; msk; msk >>= 1) e += __shfl_xor(e, msk);
  if ((o & 63) == 0) red2[wave] = e;
  __syncthreads();
  float sum = red2[0] + red2[1];
  out[b * OO + o] = (s - m) - logf(sum);
}

extern "C" void kernel_launch(void* const* d_in, const int* in_sizes, int n_in,
                              void* d_out, int out_size, void* d_ws, size_t ws_size,
                              hipStream_t stream) {
  const float* x = (const float*)d_in[0];
  const float* wih = (const float*)d_in[1];
  const float* whh = (const float*)d_in[2];
  const float* bih = (const float*)d_in[3];
  const float* bhh = (const float*)d_in[4];
  const float* who = (const float*)d_in[5];
  const float* bho = (const float*)d_in[6];
  const int* lengths = (const int*)d_in[7];
  float* out = (float*)d_out;

  char* ws = (char*)d_ws;
  float* Gb = (float*)ws;                        // 33,554,432 B
  char* hb = ws + 33554432;                      // 262,144 B (2 slots x 2 halves x 4096 records)
  float* hf = (float*)(ws + 33554432 + 262144);  // 131,072 B

  (void)hipMemsetAsync(hb, 0, 262144, stream);  // clear tags (graph-replay safety)

  phaseA_mfma<<<dim3(16, 64), 256, 0, stream>>>(x, wih, bih, bhh, Gb);
  lstm_persist<<<256, 256, 0, stream>>>(whh, Gb, lengths, hb, hf);
  finalK<<<BB, 128, 0, stream>>>(hf, who, bho, out);
}